// Round 2
// baseline (154.715 us; speedup 1.0000x reference)
//
#include <hip/hip_runtime.h>

#define EPS 1e-7f
#define N256 256
#define NB 64            // n / 4 (float4 chunks per row)
#define BQ 16            // y-rows per block
#define BLOCK 512
#define NWAVE 8          // BLOCK / 64
#define MTILE 32         // A-rows per iteration (8 waves x 4 rows)

__global__ __launch_bounds__(BLOCK, 1)
void cel_kernel(const float* __restrict__ y, const float* __restrict__ A,
                const float* __restrict__ bb, const float* __restrict__ c,
                float* __restrict__ z)
{
    __shared__ float4 ymc[BQ * NB];     // 16 KB: (y - c) tile, [j][64] float4
    __shared__ float  red[NWAVE][BQ];   // per-wave candidate mins
    __shared__ float  alphas[BQ];

    const int t = threadIdx.x;
    const int blk = blockIdx.x;
    const long base4 = (long)blk * (BQ * NB);

    const float4* y4 = (const float4*)y;
    const float4* A4 = (const float4*)A;
    const float4* c4 = (const float4*)c;
    float4* z4 = (float4*)z;

    const int lane = t & 63;
    const int w    = t >> 6;
    const int r    = lane >> 4;     // A-row subgroup within wave (0..3)
    const int c16  = lane & 15;     // 16-lane dot-product split

    // per-lane c slice (interleaved float4 columns c16 + 16k), reused all iters
    float4 cc[4];
    #pragma unroll
    for (int k = 0; k < 4; ++k) cc[k] = c4[c16 + 16 * k];

    // stage ymc = y - c (coalesced float4)
    #pragma unroll
    for (int kk = 0; kk < (BQ * NB) / BLOCK; ++kk) {
        int pos = t + kk * BLOCK;
        float4 yv = y4[base4 + pos];
        float4 cv = c4[pos & (NB - 1)];
        float4 rr;
        rr.x = yv.x - cv.x; rr.y = yv.y - cv.y;
        rr.z = yv.z - cv.z; rr.w = yv.w - cv.w;
        ymc[pos] = rr;
    }
    __syncthreads();

    float cmin[BQ];
    #pragma unroll
    for (int j = 0; j < BQ; ++j) cmin[j] = 2.0f;

    // prefetch first A slice: 4 rows/wave, coalesced (4 x 256B segments/instr)
    int row = w * 4 + r;
    float4 av[4];
    {
        const float4* ap = A4 + (long)row * NB;
        #pragma unroll
        for (int k = 0; k < 4; ++k) av[k] = ap[c16 + 16 * k];
    }

    for (int it = 0; it < N256 / MTILE; ++it) {
        // prefetch next tile's A while computing this one
        float4 avn[4];
        const int rown = row + MTILE;
        if (it + 1 < N256 / MTILE) {
            const float4* ap = A4 + (long)rown * NB;
            #pragma unroll
            for (int k = 0; k < 4; ++k) avn[k] = ap[c16 + 16 * k];
        }

        float vals[BQ + 1];
        // fused A·c partial
        {
            float s = 0.f;
            #pragma unroll
            for (int k = 0; k < 4; ++k)
                s = fmaf(av[k].x, cc[k].x, fmaf(av[k].y, cc[k].y,
                    fmaf(av[k].z, cc[k].z, fmaf(av[k].w, cc[k].w, s))));
            vals[BQ] = s;
        }
        // A-row · (y_j - c) partials from LDS broadcast (2-way bank alias = free)
        #pragma unroll
        for (int j = 0; j < BQ; ++j) {
            float s = 0.f;
            #pragma unroll
            for (int k = 0; k < 4; ++k) {
                float4 yv = ymc[j * NB + c16 + 16 * k];
                s = fmaf(av[k].x, yv.x, fmaf(av[k].y, yv.y,
                    fmaf(av[k].z, yv.z, fmaf(av[k].w, yv.w, s))));
            }
            vals[j] = s;
        }

        // 16-lane butterfly sum of all 17 partials
        #pragma unroll
        for (int off = 1; off < 16; off <<= 1) {
            #pragma unroll
            for (int i = 0; i < BQ + 1; ++i)
                vals[i] += __shfl_xor(vals[i], off);
        }

        const float bmAc = bb[row] - vals[BQ];
        #pragma unroll
        for (int j = 0; j < BQ; ++j) {
            float denom = vals[j] + EPS;
            float ip = bmAc * __builtin_amdgcn_rcpf(denom);
            float cd = (ip > 1.f || ip < 0.f) ? 2.f : ip;
            cmin[j] = fminf(cmin[j], cd);
        }

        row = rown;
        #pragma unroll
        for (int k = 0; k < 4; ++k) av[k] = avn[k];
    }

    // combine the 4 row-subgroups within the wave (lanes within a 16-group identical)
    #pragma unroll
    for (int j = 0; j < BQ; ++j) {
        float v = cmin[j];
        v = fminf(v, __shfl_xor(v, 16));
        v = fminf(v, __shfl_xor(v, 32));
        cmin[j] = v;
    }
    if (lane == 0) {
        #pragma unroll
        for (int j = 0; j < BQ; ++j) red[w][j] = cmin[j];
    }
    __syncthreads();

    if (t < BQ) {
        float a = red[0][t];
        #pragma unroll
        for (int wv = 1; wv < NWAVE; ++wv) a = fminf(a, red[wv][t]);
        alphas[t] = (a > 1.f) ? 1.f : a;
    }
    __syncthreads();

    // z = c + alpha * (y - c), coalesced float4 stores
    #pragma unroll
    for (int kk = 0; kk < (BQ * NB) / BLOCK; ++kk) {
        int pos = t + kk * BLOCK;
        int rw  = pos >> 6;
        float al = alphas[rw];
        float4 m  = ymc[pos];
        float4 cv = c4[pos & (NB - 1)];
        float4 o;
        o.x = fmaf(al, m.x, cv.x);
        o.y = fmaf(al, m.y, cv.y);
        o.z = fmaf(al, m.z, cv.z);
        o.w = fmaf(al, m.w, cv.w);
        z4[base4 + pos] = o;
    }
}

extern "C" void kernel_launch(void* const* d_in, const int* in_sizes, int n_in,
                              void* d_out, int out_size, void* d_ws, size_t ws_size,
                              hipStream_t stream) {
    const float* y = (const float*)d_in[0];
    const float* A = (const float*)d_in[1];
    const float* b = (const float*)d_in[2];
    const float* c = (const float*)d_in[3];
    float* z = (float*)d_out;

    const int B = in_sizes[0] / N256;   // 4096
    const int grid = B / BQ;            // 256

    cel_kernel<<<grid, BLOCK, 0, stream>>>(y, A, b, c, z);
}

// Round 3
// 67.474 us; speedup vs baseline: 2.2929x; 2.2929x over previous
//
#include <hip/hip_runtime.h>
#include <hip/hip_bf16.h>

#define EPS 1e-7f

typedef __attribute__((ext_vector_type(8))) short short8;
typedef __attribute__((ext_vector_type(4))) float f32x4;

// pack two floats to two bf16 (RNE) in one uint (low = first)
__device__ __forceinline__ unsigned pk(float a, float b) {
    __hip_bfloat162 h2 = __float22bfloat162_rn(make_float2(a, b));
    unsigned r; __builtin_memcpy(&r, &h2, 4); return r;
}

// ---------------------------------------------------------------------------
// K0: A(fp32,[256][256]) -> Aswz(bf16, B-fragment order)  +  Ac / bmAc
// fragment linearization: u = (T*8 + s)*64 + l  holds
//   A[16*T + (l&15)][32*s + 8*(l>>4) + i], i=0..7   (16B per lane)
// ---------------------------------------------------------------------------
__global__ __launch_bounds__(256)
void prep_kernel(const float* __restrict__ A, const float* __restrict__ bb,
                 const float* __restrict__ c, short* __restrict__ Aswz,
                 float* __restrict__ Ac, float* __restrict__ bmAc)
{
    const int blk = blockIdx.x;
    const int t = threadIdx.x;
    if (blk < 32) {
        const int u = blk * 256 + t;
        const int l = u & 63;
        const int s = (u >> 6) & 7;
        const int T = u >> 9;
        const int row = T * 16 + (l & 15);
        const int n0 = s * 32 + ((l >> 4) & 3) * 8;
        const float4* ap = (const float4*)(A + (size_t)row * 256 + n0);
        float4 f0 = ap[0];
        float4 f1 = ap[1];
        uint4 v;
        v.x = pk(f0.x, f0.y); v.y = pk(f0.z, f0.w);
        v.z = pk(f1.x, f1.y); v.w = pk(f1.z, f1.w);
        *(uint4*)(Aswz + (size_t)u * 8) = v;
    } else {
        // 64 blocks x 4 waves: one A-row dot c per wave
        const int g = blk - 32;
        const int w = t >> 6;
        const int lane = t & 63;
        const int row = g * 4 + w;
        const float4* a4 = (const float4*)(A + (size_t)row * 256);
        const float4* c4 = (const float4*)c;
        float4 av = a4[lane], cv = c4[lane];
        float p = av.x * cv.x + av.y * cv.y + av.z * cv.z + av.w * cv.w;
        #pragma unroll
        for (int off = 1; off < 64; off <<= 1) p += __shfl_xor(p, off);
        if (lane == 0) {
            Ac[row] = p;
            bmAc[row] = bb[row] - p;
        }
    }
}

// ---------------------------------------------------------------------------
// K1: per block: 16 batch rows x all 256 m.
//   8 waves, wave w owns m-tiles {2w, 2w+1}.
//   dot[b][m] via mfma_f32_16x16x32_bf16 on raw y; corrected by Ac[m].
//   row-min over m -> alpha -> z = c + alpha*(y-c). All block-local.
// ---------------------------------------------------------------------------
__global__ __launch_bounds__(512)
void gemm_kernel(const float* __restrict__ y, const float* __restrict__ c,
                 const short* __restrict__ Aswz, const float* __restrict__ Ac,
                 const float* __restrict__ bmAc, float* __restrict__ z)
{
    __shared__ float red[8][16];
    __shared__ float alphas[16];

    const int t    = threadIdx.x;
    const int w    = t >> 6;
    const int lane = t & 63;
    const int lr   = lane & 15;   // frag row (A) / col (B)
    const int lg   = lane >> 4;   // k-group
    const int b0   = blockIdx.x * 16;

    f32x4 acc0 = {0.f, 0.f, 0.f, 0.f};
    f32x4 acc1 = {0.f, 0.f, 0.f, 0.f};

    const int yrow = b0 + lr;
    const float4* yp = (const float4*)(y + (size_t)yrow * 256) + lg * 2;

    const int MT0 = w * 2, MT1 = MT0 + 1;
    const short8* bp0 = (const short8*)Aswz + (size_t)(MT0 * 8) * 64 + lane;
    const short8* bp1 = (const short8*)Aswz + (size_t)(MT1 * 8) * 64 + lane;

    #pragma unroll
    for (int s = 0; s < 8; ++s) {
        float4 f0 = yp[8 * s];      // y[row][32s+8lg .. +3]
        float4 f1 = yp[8 * s + 1];  // y[row][32s+8lg+4 .. +7]
        uint4 au;
        au.x = pk(f0.x, f0.y); au.y = pk(f0.z, f0.w);
        au.z = pk(f1.x, f1.y); au.w = pk(f1.z, f1.w);
        short8 af; __builtin_memcpy(&af, &au, 16);
        short8 bf0 = bp0[s * 64];
        short8 bf1 = bp1[s * 64];
        acc0 = __builtin_amdgcn_mfma_f32_16x16x32_bf16(af, bf0, acc0, 0, 0, 0);
        acc1 = __builtin_amdgcn_mfma_f32_16x16x32_bf16(af, bf1, acc1, 0, 0, 0);
    }

    // epilogue: cand + min over m
    const int m0 = MT0 * 16 + lr;
    const int m1 = MT1 * 16 + lr;
    const float Ac0 = Ac[m0], Ac1 = Ac[m1];
    const float bm0 = bmAc[m0], bm1 = bmAc[m1];

    float cmin[4];
    #pragma unroll
    for (int q = 0; q < 4; ++q) {
        float d0 = acc0[q] - Ac0;
        float d1 = acc1[q] - Ac1;
        float ip0 = bm0 / (d0 + EPS);
        float ip1 = bm1 / (d1 + EPS);
        float c0 = (ip0 > 1.f || ip0 < 0.f) ? 2.f : ip0;
        float c1 = (ip1 > 1.f || ip1 < 0.f) ? 2.f : ip1;
        cmin[q] = fminf(c0, c1);
    }
    #pragma unroll
    for (int q = 0; q < 4; ++q) {
        float v = cmin[q];
        v = fminf(v, __shfl_xor(v, 1));
        v = fminf(v, __shfl_xor(v, 2));
        v = fminf(v, __shfl_xor(v, 4));
        v = fminf(v, __shfl_xor(v, 8));
        cmin[q] = v;
    }
    if (lr == 0) {
        #pragma unroll
        for (int q = 0; q < 4; ++q) red[w][lg * 4 + q] = cmin[q];
    }
    __syncthreads();

    if (t < 16) {
        float a = red[0][t];
        #pragma unroll
        for (int i = 1; i < 8; ++i) a = fminf(a, red[i][t]);
        alphas[t] = fminf(a, 1.0f);   // alpha > 1 -> 1
    }
    __syncthreads();

    // z = c + alpha*(y - c): 16 rows x 64 float4, coalesced (y L2-hot)
    const float4* y4 = (const float4*)y;
    const float4* c4 = (const float4*)c;
    float4* z4 = (float4*)z;
    #pragma unroll
    for (int k = 0; k < 2; ++k) {
        int pos = t + k * 512;
        int row = pos >> 6;
        int col = pos & 63;
        float al = alphas[row];
        float4 yv = y4[(size_t)(b0 + row) * 64 + col];
        float4 cv = c4[col];
        float4 o;
        o.x = fmaf(al, yv.x - cv.x, cv.x);
        o.y = fmaf(al, yv.y - cv.y, cv.y);
        o.z = fmaf(al, yv.z - cv.z, cv.z);
        o.w = fmaf(al, yv.w - cv.w, cv.w);
        z4[(size_t)(b0 + row) * 64 + col] = o;
    }
}

extern "C" void kernel_launch(void* const* d_in, const int* in_sizes, int n_in,
                              void* d_out, int out_size, void* d_ws, size_t ws_size,
                              hipStream_t stream) {
    const float* y = (const float*)d_in[0];
    const float* A = (const float*)d_in[1];
    const float* b = (const float*)d_in[2];
    const float* c = (const float*)d_in[3];
    float* z = (float*)d_out;

    short* Aswz = (short*)d_ws;                          // 128 KB
    float* Acp  = (float*)((char*)d_ws + 65536 * 2);     // 1 KB
    float* bmAcp = Acp + 256;                            // 1 KB

    const int B = in_sizes[0] / 256;                     // 4096

    prep_kernel<<<96, 256, 0, stream>>>(A, b, c, Aswz, Acp, bmAcp);
    gemm_kernel<<<B / 16, 512, 0, stream>>>(y, c, Aswz, Acp, bmAcp, z);
}